// Round 1
// baseline (299.875 us; speedup 1.0000x reference)
//
#include <hip/hip_runtime.h>
#include <math.h>

// Problem constants (reference shapes are fixed)
constexpr int Bc = 8, Cc = 64, Hc = 256, Wc = 256, Sc = 4;
constexpr int PHn = Hc / Sc;               // 64 patch rows
constexpr int PWn = Wc / Sc;               // 64 patch cols
constexpr int NPATCH = Bc * PHn * PWn;     // 32768
constexpr int WPB = 4;                     // waves (patches) per block

__device__ __forceinline__ float sigmoidf_(float v) {
    return 1.0f / (1.0f + __expf(-v));
}

// One wave (64 lanes) per patch; lane = channel. Each lane holds its
// channel's 16 patch pixels in registers for the whole pipeline.
__global__ __launch_bounds__(256, 4)
void ciam_kernel(const float* __restrict__ x,
                 const float* __restrict__ fc_w,
                 const float* __restrict__ fc_b,
                 const float* __restrict__ c1w,
                 const float* __restrict__ c1b,
                 const float* __restrict__ c2w,
                 const float* __restrict__ c2b,
                 float* __restrict__ out)
{
    // fc_w at pitch 65: row read fcw_lds[c*65+k] -> bank (c+k)%32, 2 lanes/bank (free)
    __shared__ float fcw_lds[64 * 65];
    __shared__ float maxbuf[WPB][64];
    __shared__ float pixbuf[WPB][16 * 65];  // pixel-major, pitch 65 (conflict-free transpose)
    __shared__ float g1buf[WPB][16];

    const int tid  = threadIdx.x;
    const int wave = tid >> 6;
    const int lane = tid & 63;

    // Stage fc_w (64x64) into LDS, coalesced global reads
    #pragma unroll
    for (int i = 0; i < 16; ++i) {
        int idx = tid + i * 256;
        fcw_lds[(idx >> 6) * 65 + (idx & 63)] = fc_w[idx];
    }

    const float w10 = c1w[0], w11 = c1w[1], b1 = c1b[0];
    const float w20 = c2w[0], w21 = c2w[1], b2 = c2b[0];

    const int patch = blockIdx.x * WPB + wave;
    const int b  = patch >> 12;      // /4096
    const int l  = patch & 4095;
    const int ph = l >> 6;
    const int pw = l & 63;
    const int c  = lane;

    const size_t base = ((size_t)(b * Cc + c) * Hc + ph * Sc) * Wc + pw * Sc;

    // Load this channel's 4x4 patch pixels (4 rows of float4)
    float4 v[4];
    #pragma unroll
    for (int i = 0; i < 4; ++i)
        v[i] = *reinterpret_cast<const float4*>(x + base + (size_t)i * Wc);

    // Channel attention: per-channel max over the 16 pixels
    float mv = -3.4e38f;
    #pragma unroll
    for (int i = 0; i < 4; ++i)
        mv = fmaxf(mv, fmaxf(fmaxf(v[i].x, v[i].y), fmaxf(v[i].z, v[i].w)));
    maxbuf[wave][lane] = mv;
    __syncthreads();   // covers fc_w staging + maxbuf

    // m[c] = sigmoid(fc_b[c] + sum_k fc_w[c,k] * maxv[k])
    float acc = fc_b[c];
    #pragma unroll 16
    for (int k = 0; k < 64; ++k)
        acc = fmaf(fcw_lds[c * 65 + k], maxbuf[wave][k], acc);
    const float m = sigmoidf_(acc);

    #pragma unroll
    for (int i = 0; i < 4; ++i) {
        v[i].x *= m; v[i].y *= m; v[i].z *= m; v[i].w *= m;
    }

    // Transpose into pixel-major LDS for the per-pixel channel reductions.
    // Write: fixed pixel row j, column = lane -> stride-1, conflict-free.
    #pragma unroll
    for (int i = 0; i < 4; ++i) {
        pixbuf[wave][(i * 4 + 0) * 65 + c] = v[i].x;
        pixbuf[wave][(i * 4 + 1) * 65 + c] = v[i].y;
        pixbuf[wave][(i * 4 + 2) * 65 + c] = v[i].z;
        pixbuf[wave][(i * 4 + 3) * 65 + c] = v[i].w;
    }
    __syncthreads();

    // Per-pixel mean/max over 64 channels: 4 lanes per pixel, 16 ch each,
    // then 2-step shfl_xor combine. Read banks: (a + 16q + t)%32 -> 2 lanes/bank.
    {
        const int a = lane >> 2, q = lane & 3;
        const float* pb = &pixbuf[wave][a * 65 + q * 16];
        float s = 0.f, mx = -3.4e38f;
        #pragma unroll
        for (int t = 0; t < 16; ++t) {
            float u = pb[t];
            s += u;
            mx = fmaxf(mx, u);
        }
        s  += __shfl_xor(s, 1);
        s  += __shfl_xor(s, 2);
        mx  = fmaxf(mx, __shfl_xor(mx, 1));
        mx  = fmaxf(mx, __shfl_xor(mx, 2));
        float g1 = sigmoidf_(w10 * (s * (1.f / 64.f)) + w11 * mx + b1);
        if (q == 0) g1buf[wave][a] = g1;
    }
    __syncthreads();

    // Apply g1 (broadcast reads, conflict-free)
    #pragma unroll
    for (int i = 0; i < 4; ++i) {
        v[i].x *= g1buf[wave][i * 4 + 0];
        v[i].y *= g1buf[wave][i * 4 + 1];
        v[i].z *= g1buf[wave][i * 4 + 2];
        v[i].w *= g1buf[wave][i * 4 + 3];
    }

    // Whole-patch mean/max over all 1024 values: per-lane partial + butterfly
    float ls = 0.f, lmx = -3.4e38f;
    #pragma unroll
    for (int i = 0; i < 4; ++i) {
        ls += v[i].x + v[i].y + v[i].z + v[i].w;
        lmx = fmaxf(lmx, fmaxf(fmaxf(v[i].x, v[i].y), fmaxf(v[i].z, v[i].w)));
    }
    #pragma unroll
    for (int off = 32; off >= 1; off >>= 1) {
        ls  += __shfl_xor(ls, off);
        lmx  = fmaxf(lmx, __shfl_xor(lmx, off));
    }
    const float g2 = sigmoidf_(w20 * (ls * (1.f / 1024.f)) + w21 * lmx + b2);

    // Scale and store (same addresses as the load)
    #pragma unroll
    for (int i = 0; i < 4; ++i) {
        float4 o = v[i];
        o.x *= g2; o.y *= g2; o.z *= g2; o.w *= g2;
        *reinterpret_cast<float4*>(out + base + (size_t)i * Wc) = o;
    }
}

extern "C" void kernel_launch(void* const* d_in, const int* in_sizes, int n_in,
                              void* d_out, int out_size, void* d_ws, size_t ws_size,
                              hipStream_t stream) {
    const float* x    = (const float*)d_in[0];
    const float* fc_w = (const float*)d_in[1];
    const float* fc_b = (const float*)d_in[2];
    const float* c1w  = (const float*)d_in[3];
    const float* c1b  = (const float*)d_in[4];
    const float* c2w  = (const float*)d_in[5];
    const float* c2b  = (const float*)d_in[6];
    // d_in[7] = size (int, ==4) -- shapes hardcoded to the reference.

    float* out = (float*)d_out;
    ciam_kernel<<<NPATCH / WPB, 256, 0, stream>>>(x, fc_w, fc_b, c1w, c1b, c2w, c2b, out);
}

// Round 2
// 258.169 us; speedup vs baseline: 1.1615x; 1.1615x over previous
//
#include <hip/hip_runtime.h>
#include <math.h>

// Problem constants (reference shapes are fixed)
constexpr int Bc = 8, Cc = 64, Hc = 256, Wc = 256, Sc = 4;
constexpr int NPATCH = Bc * (Hc / Sc) * (Wc / Sc);  // 32768
constexpr int TP = 8;          // patches per block (32 contiguous columns)
constexpr int CPITCH = 133;    // tile: per-channel pitch in floats (5*c mod 32 -> 2-way, free)
constexpr int RPITCH = 33;     // tile: per-row pitch within a channel (4 rows x 32 cols + pad)

__device__ __forceinline__ float sigmoidf_(float v) {
    return 1.0f / (1.0f + __expf(-v));
}

// Block = 256 threads (4 waves) handles 8 adjacent patches (one b, ph, 32-col strip).
// Stage-in/out through LDS is fully coalesced (8 x 128B lines per wave instruction).
// Compute: wave w owns patches {2w, 2w+1}, lane = channel (round-1 proven pipeline).
__global__ __launch_bounds__(256, 2)
void ciam_kernel(const float* __restrict__ x,
                 const float* __restrict__ fc_w,
                 const float* __restrict__ fc_b,
                 const float* __restrict__ c1w,
                 const float* __restrict__ c1b,
                 const float* __restrict__ c2w,
                 const float* __restrict__ c2b,
                 float* __restrict__ out)
{
    __shared__ float T[64 * CPITCH];        // 34048 B  tile, channel-major
    __shared__ float fcw_lds[64 * 65];      // 16640 B  fc_w at pitch 65 (conflict-free)
    __shared__ float maxbuf[TP][64];        //  2048 B  per-patch channel maxes
    __shared__ float pixbuf[4][16 * 65];    // 16640 B  per-wave pixel-major transpose
    __shared__ float g1buf[4][2][16];       //   512 B  per-wave per-patch pixel gates
    // total ~69.9 KB -> 2 blocks/CU

    const int tid  = threadIdx.x;
    const int gid  = blockIdx.x;
    const int b    = gid >> 9;          // 512 blocks per batch (64 ph x 8 pwg)
    const int rem  = gid & 511;
    const int ph   = rem >> 3;
    const int pwg  = rem & 7;
    const int col0 = pwg * 32;

    // ---- Stage fc_w (64x64) into LDS, coalesced float4 reads ----
    #pragma unroll
    for (int i = 0; i < 4; ++i) {
        int u   = i * 256 + tid;        // 1024 float4 units
        int row = u >> 4;
        int jf  = (u & 15) << 2;
        const float4 wv = *reinterpret_cast<const float4*>(fc_w + row * 64 + jf);
        float* fd = &fcw_lds[row * 65 + jf];
        fd[0] = wv.x; fd[1] = wv.y; fd[2] = wv.z; fd[3] = wv.w;
    }

    // ---- Stage tile: 64ch x 4rows x 32cols, coalesced (8 lanes per 128B segment) ----
    #pragma unroll
    for (int i = 0; i < 8; ++i) {
        int u   = i * 256 + tid;        // 2048 float4 units
        int seg = u >> 3;               // 256 segments: (c, r)
        int c_  = seg >> 2;
        int r_  = seg & 3;
        int j4  = (u & 7) << 2;
        const float4 val = *reinterpret_cast<const float4*>(
            x + (((size_t)(b * Cc + c_) * Hc + (ph * Sc + r_)) * Wc + col0 + j4));
        float* td = &T[c_ * CPITCH + r_ * RPITCH + j4];
        td[0] = val.x; td[1] = val.y; td[2] = val.z; td[3] = val.w;
    }

    const float w10 = c1w[0], w11 = c1w[1], b1 = c1b[0];
    const float w20 = c2w[0], w21 = c2w[1], b2 = c2b[0];

    __syncthreads();

    const int wave = tid >> 6;
    const int lane = tid & 63;
    const int c    = lane;
    const int p0   = wave * 2;          // this wave's two patches

    // ---- Read both patches' 16 pixels for this lane's channel (2-way banks = free) ----
    float v[2][16];
    #pragma unroll
    for (int pi = 0; pi < 2; ++pi) {
        const float* tp = &T[c * CPITCH + (p0 + pi) * 4];
        #pragma unroll
        for (int r = 0; r < 4; ++r)
            #pragma unroll
            for (int j = 0; j < 4; ++j)
                v[pi][r * 4 + j] = tp[r * RPITCH + j];
    }

    // ---- Channel attention: per-channel max -> FC -> sigmoid ----
    float mx0 = -3.4e38f, mx1 = -3.4e38f;
    #pragma unroll
    for (int t = 0; t < 16; ++t) {
        mx0 = fmaxf(mx0, v[0][t]);
        mx1 = fmaxf(mx1, v[1][t]);
    }
    maxbuf[p0][c]     = mx0;
    maxbuf[p0 + 1][c] = mx1;
    __syncthreads();

    float a0 = fc_b[c], a1 = a0;
    #pragma unroll 16
    for (int k = 0; k < 64; ++k) {
        float wv = fcw_lds[c * 65 + k];          // 2-way banks, free
        a0 = fmaf(wv, maxbuf[p0][k], a0);        // broadcast, free
        a1 = fmaf(wv, maxbuf[p0 + 1][k], a1);
    }
    const float m0 = sigmoidf_(a0), m1 = sigmoidf_(a1);
    #pragma unroll
    for (int t = 0; t < 16; ++t) { v[0][t] *= m0; v[1][t] *= m1; }

    // ---- Per-pixel channel mean/max gate (via per-wave pixel-major transpose) ----
    #pragma unroll
    for (int pi = 0; pi < 2; ++pi) {
        #pragma unroll
        for (int t = 0; t < 16; ++t)
            pixbuf[wave][t * 65 + c] = v[pi][t];   // stride-1 writes, conflict-free
        __syncthreads();
        {
            const int a = lane >> 2, q = lane & 3; // 4 lanes per pixel, 16 ch each
            const float* pb = &pixbuf[wave][a * 65 + q * 16];
            float s = 0.f, mxp = -3.4e38f;
            #pragma unroll
            for (int t = 0; t < 16; ++t) {
                float u = pb[t];
                s += u;
                mxp = fmaxf(mxp, u);
            }
            s   += __shfl_xor(s, 1);
            s   += __shfl_xor(s, 2);
            mxp  = fmaxf(mxp, __shfl_xor(mxp, 1));
            mxp  = fmaxf(mxp, __shfl_xor(mxp, 2));
            float g1 = sigmoidf_(w10 * (s * (1.f / 64.f)) + w11 * mxp + b1);
            if (q == 0) g1buf[wave][pi][a] = g1;
        }
        __syncthreads();
        #pragma unroll
        for (int t = 0; t < 16; ++t)
            v[pi][t] *= g1buf[wave][pi][t];        // broadcast, free
    }

    // ---- Whole-patch mean/max gate, then write gated values back to tile ----
    #pragma unroll
    for (int pi = 0; pi < 2; ++pi) {
        float ls = 0.f, lmx = -3.4e38f;
        #pragma unroll
        for (int t = 0; t < 16; ++t) {
            ls += v[pi][t];
            lmx = fmaxf(lmx, v[pi][t]);
        }
        #pragma unroll
        for (int off = 32; off >= 1; off >>= 1) {
            ls  += __shfl_xor(ls, off);
            lmx  = fmaxf(lmx, __shfl_xor(lmx, off));
        }
        const float g2 = sigmoidf_(w20 * (ls * (1.f / 1024.f)) + w21 * lmx + b2);
        float* tp = &T[c * CPITCH + (p0 + pi) * 4];
        #pragma unroll
        for (int r = 0; r < 4; ++r)
            #pragma unroll
            for (int j = 0; j < 4; ++j)
                tp[r * RPITCH + j] = v[pi][r * 4 + j] * g2;
    }
    __syncthreads();

    // ---- Stage-out: coalesced float4 stores (same mapping as stage-in) ----
    #pragma unroll
    for (int i = 0; i < 8; ++i) {
        int u   = i * 256 + tid;
        int seg = u >> 3;
        int c_  = seg >> 2;
        int r_  = seg & 3;
        int j4  = (u & 7) << 2;
        const float* ts = &T[c_ * CPITCH + r_ * RPITCH + j4];
        float4 o;
        o.x = ts[0]; o.y = ts[1]; o.z = ts[2]; o.w = ts[3];
        *reinterpret_cast<float4*>(
            out + (((size_t)(b * Cc + c_) * Hc + (ph * Sc + r_)) * Wc + col0 + j4)) = o;
    }
}

extern "C" void kernel_launch(void* const* d_in, const int* in_sizes, int n_in,
                              void* d_out, int out_size, void* d_ws, size_t ws_size,
                              hipStream_t stream) {
    const float* x    = (const float*)d_in[0];
    const float* fc_w = (const float*)d_in[1];
    const float* fc_b = (const float*)d_in[2];
    const float* c1w  = (const float*)d_in[3];
    const float* c1b  = (const float*)d_in[4];
    const float* c2w  = (const float*)d_in[5];
    const float* c2b  = (const float*)d_in[6];
    // d_in[7] = size (int, ==4) -- shapes hardcoded to the reference.

    float* out = (float*)d_out;
    ciam_kernel<<<NPATCH / TP, 256, 0, stream>>>(x, fc_w, fc_b, c1w, c1b, c2w, c2b, out);
}